// Round 1
// baseline (1730.032 us; speedup 1.0000x reference)
//
#include <hip/hip_runtime.h>
#include <math.h>

#define NW 960
#define NT 144
#define DIM 192
#define NH 6
#define HD 32
#define WCOLS 576

// ---------------------------------------------------------------------------
// Kernel 1: one block per (window, head). QKV projection + biased/masked
// softmax attention. Writes pre-projection output (w, n, h*32+dd) to out.
// LDS plan (floats):
//   phase A/B:  xt[32][149] @0 (4768), wt[32][96] @4768 (3072)   -> 7840
//   phase C+ :  qs[144][33] @0, ks @4752, vs[144][34] @9504      -> 14400
//   S[32][148] @14400 (4736)                                     -> 19136 (76.5KB)
// 2 blocks/CU (153KB LDS), 8 waves/CU.
// ---------------------------------------------------------------------------
__global__ __launch_bounds__(256, 2)
void attn_kernel(const float* __restrict__ x, const int* __restrict__ mask,
                 const int* __restrict__ rel_index, const float* __restrict__ w_qkv,
                 const float* __restrict__ b_qkv, const float* __restrict__ bias_table,
                 float* __restrict__ out)
{
    __shared__ float smem[19136];
    float* xt = smem;             // [32][149]
    float* wt = smem + 4768;      // [32][96]
    float* qs = smem;             // [144][33]  (aliases xt/wt after barrier)
    float* ks = smem + 4752;      // [144][33]
    float* vs = smem + 9504;      // [144][34]
    float* S  = smem + 14400;     // [32][148]

    const int t  = threadIdx.x;
    const int w  = blockIdx.x / NH;   // consecutive blocks share a window -> L2 reuse of x
    const int h  = blockIdx.x % NH;
    const int tx = t & 15;
    const int ty = t >> 4;
    const float scale = 0.17677669529663687f;  // 1/sqrt(32)

    const float* xg = x + (size_t)w * NT * DIM;

    // ---- QKV gemm: (144 x 96) = x[w] (144x192) @ w_qkv slice, K tiled by 32.
    // thread (tx,ty): rows ty*9..+8, cols tx*6..+5 (54 accumulators)
    float acc[9][6];
    #pragma unroll
    for (int i = 0; i < 9; ++i)
        #pragma unroll
        for (int j = 0; j < 6; ++j) acc[i][j] = 0.f;

    for (int kt = 0; kt < 6; ++kt) {
        #pragma unroll
        for (int l = 0; l < 18; ++l) {               // xt[kk][n] = x[n][kt*32+kk]
            int e = t + l * 256;
            int n = e >> 5, kk = e & 31;
            xt[kk * 149 + n] = xg[n * DIM + kt * 32 + kk];
        }
        #pragma unroll
        for (int l = 0; l < 12; ++l) {               // wt[kk][c], c -> (part,jj)
            int e = t + l * 256;
            int kk = e / 96, c = e - kk * 96;
            int col = (c >> 5) * DIM + h * HD + (c & 31);
            wt[kk * 96 + c] = w_qkv[(kt * 32 + kk) * WCOLS + col];
        }
        __syncthreads();
        #pragma unroll
        for (int kk = 0; kk < 32; ++kk) {
            float a[9], b[6];
            #pragma unroll
            for (int i = 0; i < 9; ++i) a[i] = xt[kk * 149 + ty * 9 + i];
            #pragma unroll
            for (int j = 0; j < 6; ++j) b[j] = wt[kk * 96 + tx * 6 + j];
            #pragma unroll
            for (int i = 0; i < 9; ++i)
                #pragma unroll
                for (int j = 0; j < 6; ++j) acc[i][j] = fmaf(a[i], b[j], acc[i][j]);
        }
        __syncthreads();
    }

    // ---- scatter q (pre-scaled), k, v into LDS (aliases staging region)
    #pragma unroll
    for (int j = 0; j < 6; ++j) {
        int c = tx * 6 + j;
        int part = c >> 5, jj = c & 31;
        float bq = b_qkv[part * DIM + h * HD + jj];
        #pragma unroll
        for (int i = 0; i < 9; ++i) {
            int r = ty * 9 + i;
            float val = acc[i][j] + bq;
            if (part == 0)      qs[r * 33 + jj] = val * scale;
            else if (part == 1) ks[r * 33 + jj] = val;
            else                vs[r * 34 + jj] = val;
        }
    }
    __syncthreads();

    // ---- attention in row-tiles of 32 (last tile = 16 rows)
    const int wave = t >> 6, lane = t & 63;
    for (int rt = 0; rt < 5; ++rt) {
        const int rows = (rt == 4) ? 16 : 32;

        // S = q_tile @ k^T : thread = 2 rows x 9 cols outer product
        {
            int r0 = ty * 2;
            int n0 = rt * 32 + r0; if (n0 > NT - 1) n0 = NT - 1;
            int n1 = n0 + 1;       if (n1 > NT - 1) n1 = NT - 1;
            int m0 = tx * 9;
            float s0[9], s1[9];
            #pragma unroll
            for (int j = 0; j < 9; ++j) { s0[j] = 0.f; s1[j] = 0.f; }
            #pragma unroll
            for (int kk = 0; kk < 32; ++kk) {
                float a0 = qs[n0 * 33 + kk];
                float a1 = qs[n1 * 33 + kk];
                #pragma unroll
                for (int j = 0; j < 9; ++j) {
                    float bk = ks[(m0 + j) * 33 + kk];
                    s0[j] = fmaf(a0, bk, s0[j]);
                    s1[j] = fmaf(a1, bk, s1[j]);
                }
            }
            if (r0 < rows) {
                #pragma unroll
                for (int j = 0; j < 9; ++j) S[r0 * 148 + m0 + j] = s0[j];
                #pragma unroll
                for (int j = 0; j < 9; ++j) S[(r0 + 1) * 148 + m0 + j] = s1[j];
            }
        }
        __syncthreads();

        // softmax: one wave per row; bias gather + mask fused here (coalesced in m)
        for (int r = wave; r < rows; r += 4) {
            int n = rt * 32 + r;
            const int* mrow = mask + ((size_t)w * NT + n) * NT;
            const int* rrow = rel_index + n * NT;
            float e0 = S[r * 148 + lane] + bias_table[rrow[lane] * NH + h];
            if (mrow[lane] == 0) e0 = -1e9f;
            float e1 = S[r * 148 + 64 + lane] + bias_table[rrow[64 + lane] * NH + h];
            if (mrow[64 + lane] == 0) e1 = -1e9f;
            float e2 = -INFINITY;
            if (lane < 16) {
                e2 = S[r * 148 + 128 + lane] + bias_table[rrow[128 + lane] * NH + h];
                if (mrow[128 + lane] == 0) e2 = -1e9f;
            }
            float vmax = fmaxf(fmaxf(e0, e1), e2);
            #pragma unroll
            for (int off = 32; off > 0; off >>= 1)
                vmax = fmaxf(vmax, __shfl_xor(vmax, off, 64));
            float p0 = __expf(e0 - vmax);
            float p1 = __expf(e1 - vmax);
            float p2 = (lane < 16) ? __expf(e2 - vmax) : 0.f;
            float s = p0 + p1 + p2;
            #pragma unroll
            for (int off = 32; off > 0; off >>= 1)
                s += __shfl_xor(s, off, 64);
            float rinv = 1.f / s;
            S[r * 148 + lane] = p0 * rinv;
            S[r * 148 + 64 + lane] = p1 * rinv;
            if (lane < 16) S[r * 148 + 128 + lane] = p2 * rinv;
        }
        __syncthreads();

        // PV: thread = 2 rows x 2 dd; v read as float2 (conflict-free, pad 34)
        {
            int r0 = ty * 2, dd0 = tx * 2;
            if (r0 < rows) {
                float o00 = 0, o01 = 0, o10 = 0, o11 = 0;
                #pragma unroll
                for (int m = 0; m < NT; ++m) {
                    float p0 = S[r0 * 148 + m];
                    float p1 = S[(r0 + 1) * 148 + m];
                    float2 vv = *(const float2*)&vs[m * 34 + dd0];
                    o00 = fmaf(p0, vv.x, o00);
                    o01 = fmaf(p0, vv.y, o01);
                    o10 = fmaf(p1, vv.x, o10);
                    o11 = fmaf(p1, vv.y, o11);
                }
                int n0 = rt * 32 + r0;
                float2 w0 = make_float2(o00, o01);
                float2 w1 = make_float2(o10, o11);
                *(float2*)&out[((size_t)(w * NT + n0)) * DIM + h * HD + dd0] = w0;
                *(float2*)&out[((size_t)(w * NT + n0 + 1)) * DIM + h * HD + dd0] = w1;
            }
        }
        __syncthreads();
    }
}

// ---------------------------------------------------------------------------
// Kernel 2: out-proj (138240 x 192) @ (192 x 192) + b_out, IN PLACE on d_out.
// Block owns 64 rows exclusively: loads them to LDS first -> in-place safe.
// ---------------------------------------------------------------------------
__global__ __launch_bounds__(256, 2)
void proj_kernel(float* __restrict__ io, const float* __restrict__ w_out,
                 const float* __restrict__ b_out)
{
    __shared__ float in_t[64 * 196];   // rows padded to 196 (float4-aligned, 2-way max)
    __shared__ float wt[32 * 192];
    const int t = threadIdx.x;
    const size_t row0 = (size_t)blockIdx.x * 64;

    #pragma unroll
    for (int l = 0; l < 12; ++l) {     // 3072 float4s
        int e = t + l * 256;
        int r = e / 48, c4 = e - r * 48;
        float4 val = *(const float4*)&io[(row0 + r) * DIM + c4 * 4];
        *(float4*)&in_t[r * 196 + c4 * 4] = val;
    }
    const int tx = t & 15, ty = t >> 4;  // tx: 12 cols, ty: 4 rows
    float acc[4][12];
    #pragma unroll
    for (int i = 0; i < 4; ++i)
        #pragma unroll
        for (int j = 0; j < 12; ++j) acc[i][j] = 0.f;

    for (int kt = 0; kt < 6; ++kt) {
        __syncthreads();                 // protect wt (and cover in_t on kt=0)
        #pragma unroll
        for (int l = 0; l < 6; ++l) {    // 1536 float4s
            int e = t + l * 256;
            int kk = e / 48, c4 = e - kk * 48;
            *(float4*)&wt[kk * 192 + c4 * 4] =
                *(const float4*)&w_out[(kt * 32 + kk) * DIM + c4 * 4];
        }
        __syncthreads();
        #pragma unroll
        for (int kk = 0; kk < 32; ++kk) {
            float a[4];
            #pragma unroll
            for (int i = 0; i < 4; ++i) a[i] = in_t[(ty * 4 + i) * 196 + kt * 32 + kk];
            float b[12];
            #pragma unroll
            for (int j4 = 0; j4 < 3; ++j4) {
                float4 bb = *(const float4*)&wt[kk * 192 + tx * 12 + j4 * 4];
                b[j4 * 4] = bb.x; b[j4 * 4 + 1] = bb.y;
                b[j4 * 4 + 2] = bb.z; b[j4 * 4 + 3] = bb.w;
            }
            #pragma unroll
            for (int i = 0; i < 4; ++i)
                #pragma unroll
                for (int j = 0; j < 12; ++j)
                    acc[i][j] = fmaf(a[i], b[j], acc[i][j]);
        }
    }

    float bo[12];
    #pragma unroll
    for (int j4 = 0; j4 < 3; ++j4) {
        float4 bb = *(const float4*)&b_out[tx * 12 + j4 * 4];
        bo[j4 * 4] = bb.x; bo[j4 * 4 + 1] = bb.y;
        bo[j4 * 4 + 2] = bb.z; bo[j4 * 4 + 3] = bb.w;
    }
    #pragma unroll
    for (int i = 0; i < 4; ++i) {
        size_t r = row0 + ty * 4 + i;
        #pragma unroll
        for (int j4 = 0; j4 < 3; ++j4) {
            float4 o;
            o.x = acc[i][j4 * 4]     + bo[j4 * 4];
            o.y = acc[i][j4 * 4 + 1] + bo[j4 * 4 + 1];
            o.z = acc[i][j4 * 4 + 2] + bo[j4 * 4 + 2];
            o.w = acc[i][j4 * 4 + 3] + bo[j4 * 4 + 3];
            *(float4*)&io[r * DIM + tx * 12 + j4 * 4] = o;
        }
    }
}

extern "C" void kernel_launch(void* const* d_in, const int* in_sizes, int n_in,
                              void* d_out, int out_size, void* d_ws, size_t ws_size,
                              hipStream_t stream) {
    const float* x          = (const float*)d_in[0];
    const int*   mask       = (const int*)d_in[1];
    const int*   rel_index  = (const int*)d_in[2];
    const float* w_qkv      = (const float*)d_in[3];
    const float* b_qkv      = (const float*)d_in[4];
    const float* w_out      = (const float*)d_in[5];
    const float* b_out      = (const float*)d_in[6];
    const float* bias_table = (const float*)d_in[7];
    float* out = (float*)d_out;

    hipLaunchKernelGGL(attn_kernel, dim3(NW * NH), dim3(256), 0, stream,
                       x, mask, rel_index, w_qkv, b_qkv, bias_table, out);
    hipLaunchKernelGGL(proj_kernel, dim3(NW * NT / 64), dim3(256), 0, stream,
                       out, w_out, b_out);
}

// Round 2
// 762.618 us; speedup vs baseline: 2.2685x; 2.2685x over previous
//
#include <hip/hip_runtime.h>
#include <math.h>

#define NW 960
#define NT 144
#define DIM 192
#define NH 6
#define HD 32
#define WCOLS 576

typedef __bf16 bf16x8 __attribute__((ext_vector_type(8)));
typedef float floatx4 __attribute__((ext_vector_type(4)));

__device__ __forceinline__ unsigned short f2bf(float x) {
    union { float f; unsigned u; } v; v.f = x;
    unsigned r = v.u + 0x7fffu + ((v.u >> 16) & 1u);
    return (unsigned short)(r >> 16);
}
__device__ __forceinline__ float bf2f(unsigned short b) {
    union { unsigned u; float f; } v; v.u = ((unsigned)b) << 16;
    return v.f;
}
__device__ __forceinline__ floatx4 mfma16(bf16x8 a, bf16x8 b, floatx4 c) {
    return __builtin_amdgcn_mfma_f32_16x16x32_bf16(a, b, c, 0, 0, 0);
}

// ===========================================================================
// Prep kernels (fill d_ws each call; ws is re-poisoned before every launch)
// ===========================================================================
__global__ void prep_bias(const int* __restrict__ rel_index,
                          const float* __restrict__ bias_table,
                          float* __restrict__ bias_pre) {
    int i = blockIdx.x * 256 + threadIdx.x;           // [6][144][144]
    if (i < NH * NT * NT) {
        int h = i / (NT * NT);
        int rem = i - h * (NT * NT);
        bias_pre[i] = bias_table[rel_index[rem] * NH + h];
    }
}

__global__ void prep_wqkv(const float* __restrict__ w_qkv,
                          unsigned short* __restrict__ wqt_h,
                          unsigned short* __restrict__ wqt_l) {
    int i = blockIdx.x * 256 + threadIdx.x;           // [6][96][192]
    if (i < NH * 96 * DIM) {
        int h = i / (96 * DIM);
        int rem = i - h * (96 * DIM);
        int c = rem / DIM, k = rem - c * DIM;
        float v = w_qkv[k * WCOLS + (c >> 5) * DIM + h * HD + (c & 31)];
        unsigned short hi = f2bf(v);
        wqt_h[i] = hi;
        wqt_l[i] = f2bf(v - bf2f(hi));
    }
}

__global__ void prep_wout(const float* __restrict__ w_out,
                          unsigned short* __restrict__ wt_h,
                          unsigned short* __restrict__ wt_l) {
    int i = blockIdx.x * 256 + threadIdx.x;           // [192 c][192 k]
    if (i < DIM * DIM) {
        int c = i / DIM, k = i - c * DIM;
        float v = w_out[k * DIM + c];
        unsigned short hi = f2bf(v);
        wt_h[i] = hi;
        wt_l[i] = f2bf(v - bf2f(hi));
    }
}

// ===========================================================================
// Fused attention, MFMA version. Block = 192 threads (3 waves), per (w,h).
// LDS (shorts): region1 @0 (19200):
//   phase A: XS_h[144][40]@0, XS_l@5760, WS_h[96][40]@11520, WS_l@15360
//   phase B: Q[144][40]@0, K[144][40]@5760, Vt[32][152]@11520
// P[48][152] @19200  -> total 26496 shorts = 52992 B
// ===========================================================================
__global__ __launch_bounds__(192, 2)
void attn_mfma(const float* __restrict__ x, const int* __restrict__ mask,
               const float* __restrict__ bias_pre,
               const unsigned short* __restrict__ wqt_h,
               const unsigned short* __restrict__ wqt_l,
               const float* __restrict__ b_qkv, float* __restrict__ out)
{
    __shared__ __align__(16) unsigned short lds[26496];
    unsigned short* XS_h = lds;            // [144][40]
    unsigned short* XS_l = lds + 5760;
    unsigned short* WS_h = lds + 11520;    // [96][40]
    unsigned short* WS_l = lds + 15360;
    unsigned short* Q  = lds;              // [144][40]
    unsigned short* K  = lds + 5760;       // [144][40]
    unsigned short* Vt = lds + 11520;      // [32][152]
    unsigned short* P  = lds + 19200;      // [48][152]

    const int t = threadIdx.x;
    const int w = blockIdx.x / NH;
    const int h = blockIdx.x % NH;
    const int lane = t & 63, wv = t >> 6;
    const int c = lane & 15, q = lane >> 4;
    const float scale = 0.17677669529663687f;

    const float* xg = x + (size_t)w * NT * DIM;
    const unsigned short* wqh = wqt_h + h * 96 * DIM;
    const unsigned short* wql = wqt_l + h * 96 * DIM;

    // ---------------- Phase A: QKV gemm (144x96, K=192), split hi/lo -------
    floatx4 acc[3][6];
    #pragma unroll
    for (int i = 0; i < 3; ++i)
        #pragma unroll
        for (int j = 0; j < 6; ++j) acc[i][j] = (floatx4)0.0f;

    for (int kt = 0; kt < 6; ++kt) {
        __syncthreads();
        // stage X slice [144][32] as hi/lo bf16 (float2 reads, u32 writes)
        #pragma unroll
        for (int l = 0; l < 12; ++l) {
            int e = t + l * 192;
            int n = e >> 4, kk2 = (e & 15) * 2;
            float2 xv = *(const float2*)&xg[n * DIM + kt * 32 + kk2];
            unsigned short h0 = f2bf(xv.x), h1 = f2bf(xv.y);
            unsigned short l0 = f2bf(xv.x - bf2f(h0)), l1 = f2bf(xv.y - bf2f(h1));
            *(unsigned*)&XS_h[n * 40 + kk2] = (unsigned)h0 | ((unsigned)h1 << 16);
            *(unsigned*)&XS_l[n * 40 + kk2] = (unsigned)l0 | ((unsigned)l1 << 16);
        }
        // stage W slice [96][32] from pre-transposed bf16 (uint2 = 4 shorts)
        #pragma unroll
        for (int l = 0; l < 4; ++l) {
            int e = t + l * 192;
            int cc = e >> 3, k4 = (e & 7) * 4;
            *(uint2*)&WS_h[cc * 40 + k4] = *(const uint2*)&wqh[cc * DIM + kt * 32 + k4];
            *(uint2*)&WS_l[cc * 40 + k4] = *(const uint2*)&wql[cc * DIM + kt * 32 + k4];
        }
        __syncthreads();

        bf16x8 ah[3], al[3];
        #pragma unroll
        for (int i = 0; i < 3; ++i) {
            int row = (3 * wv + i) * 16 + c;
            ah[i] = *(const bf16x8*)&XS_h[row * 40 + q * 8];
            al[i] = *(const bf16x8*)&XS_l[row * 40 + q * 8];
        }
        #pragma unroll
        for (int j = 0; j < 6; ++j) {
            int cr = j * 16 + c;
            bf16x8 bh = *(const bf16x8*)&WS_h[cr * 40 + q * 8];
            bf16x8 bl = *(const bf16x8*)&WS_l[cr * 40 + q * 8];
            #pragma unroll
            for (int i = 0; i < 3; ++i) {
                acc[i][j] = mfma16(ah[i], bh, acc[i][j]);
                acc[i][j] = mfma16(al[i], bh, acc[i][j]);
                acc[i][j] = mfma16(ah[i], bl, acc[i][j]);
            }
        }
    }
    __syncthreads();

    // ---------------- transition: write Q (pre-scaled), K, Vt (bf16) -------
    #pragma unroll
    for (int j = 0; j < 6; ++j) {
        int part = j >> 1, jj = (j & 1) * 16 + c;
        float bq = b_qkv[part * DIM + h * HD + jj];
        #pragma unroll
        for (int i = 0; i < 3; ++i) {
            int mt = 3 * wv + i;
            #pragma unroll
            for (int r = 0; r < 4; ++r) {
                int n = mt * 16 + q * 4 + r;
                float v = acc[i][j][r] + bq;
                if (part == 0)      Q[n * 40 + jj] = f2bf(v * scale);
                else if (part == 1) K[n * 40 + jj] = f2bf(v);
                else                Vt[jj * 152 + n] = f2bf(v);
            }
        }
    }
    __syncthreads();

    // ---------------- Phase B: barrier-free per-wave strips ----------------
    for (int it = 0; it < 3; ++it) {
        int s = wv + 3 * it;          // strip 0..8
        int n0 = s * 16;

        // S = Q_strip @ K^T : 9 single-bf16 MFMAs
        bf16x8 qf = *(const bf16x8*)&Q[(n0 + c) * 40 + q * 8];
        floatx4 sacc[9];
        #pragma unroll
        for (int nt = 0; nt < 9; ++nt) {
            bf16x8 kf = *(const bf16x8*)&K[(nt * 16 + c) * 40 + q * 8];
            sacc[nt] = mfma16(qf, kf, (floatx4)0.0f);
        }

        // in-register softmax: lane holds rows q*4+r, cols nt*16+c
        #pragma unroll
        for (int r = 0; r < 4; ++r) {
            int n = n0 + q * 4 + r;
            const float* brow = bias_pre + h * (NT * NT) + n * NT;
            const int* mrow = mask + ((size_t)w * NT + n) * NT;
            float e[9]; float mx = -1e30f;
            #pragma unroll
            for (int nt = 0; nt < 9; ++nt) {
                int m = nt * 16 + c;
                float val = sacc[nt][r] + brow[m];
                if (mrow[m] == 0) val = -1e9f;
                e[nt] = val;
                mx = fmaxf(mx, val);
            }
            #pragma unroll
            for (int o = 8; o; o >>= 1) mx = fmaxf(mx, __shfl_xor(mx, o, 64));
            float sum = 0.f;
            #pragma unroll
            for (int nt = 0; nt < 9; ++nt) { e[nt] = __expf(e[nt] - mx); sum += e[nt]; }
            #pragma unroll
            for (int o = 8; o; o >>= 1) sum += __shfl_xor(sum, o, 64);
            float rinv = 1.0f / sum;
            #pragma unroll
            for (int nt = 0; nt < 9; ++nt)
                P[(wv * 16 + q * 4 + r) * 152 + nt * 16 + c] = f2bf(e[nt] * rinv);
        }

        // PV: K=144 as 4 full k-steps + 1 half-masked step (A zeroed, k 112..127)
        floatx4 oacc[2];
        oacc[0] = (floatx4)0.0f; oacc[1] = (floatx4)0.0f;
        #pragma unroll
        for (int kt5 = 0; kt5 < 5; ++kt5) {
            int kb = (kt5 < 4) ? kt5 * 32 : 112;
            bf16x8 pf;
            if (kt5 == 4 && q < 2) pf = (bf16x8)(__bf16)0.0f;
            else pf = *(const bf16x8*)&P[(wv * 16 + c) * 152 + kb + q * 8];
            #pragma unroll
            for (int ntv = 0; ntv < 2; ++ntv) {
                bf16x8 vf = *(const bf16x8*)&Vt[(ntv * 16 + c) * 152 + kb + q * 8];
                oacc[ntv] = mfma16(pf, vf, oacc[ntv]);
            }
        }
        #pragma unroll
        for (int r = 0; r < 4; ++r) {
            int n = n0 + q * 4 + r;
            float* orow = out + ((size_t)(w * NT + n)) * DIM + h * HD;
            orow[c] = oacc[0][r];
            orow[16 + c] = oacc[1][r];
        }
    }
}

// ===========================================================================
// Out-proj, MFMA split, IN PLACE on d_out. Block = 256 thr (4 waves), 64 rows.
// LDS (shorts): AS_h[64][40]@0, AS_l@2560, WS_h[192][40]@5120, WS_l@12800
//   -> 20480 shorts = 40960 B
// ===========================================================================
__global__ __launch_bounds__(256, 3)
void proj_mfma(float* __restrict__ io,
               const unsigned short* __restrict__ wt_h,
               const unsigned short* __restrict__ wt_l,
               const float* __restrict__ b_out)
{
    __shared__ __align__(16) unsigned short lds[20480];
    unsigned short* AS_h = lds;            // [64][40]
    unsigned short* AS_l = lds + 2560;
    unsigned short* WS_h = lds + 5120;     // [192][40]
    unsigned short* WS_l = lds + 12800;

    const int t = threadIdx.x;
    const int lane = t & 63, wv = t >> 6;
    const int c = lane & 15, q = lane >> 4;
    const size_t row0 = (size_t)blockIdx.x * 64;

    floatx4 acc[12];
    #pragma unroll
    for (int j = 0; j < 12; ++j) acc[j] = (floatx4)0.0f;

    for (int kt = 0; kt < 6; ++kt) {
        __syncthreads();
        #pragma unroll
        for (int l = 0; l < 4; ++l) {       // A slice [64][32] fp32 -> hi/lo
            int e = t + l * 256;
            int r = e >> 4, kk2 = (e & 15) * 2;
            float2 av = *(const float2*)&io[(row0 + r) * DIM + kt * 32 + kk2];
            unsigned short h0 = f2bf(av.x), h1 = f2bf(av.y);
            unsigned short l0 = f2bf(av.x - bf2f(h0)), l1 = f2bf(av.y - bf2f(h1));
            *(unsigned*)&AS_h[r * 40 + kk2] = (unsigned)h0 | ((unsigned)h1 << 16);
            *(unsigned*)&AS_l[r * 40 + kk2] = (unsigned)l0 | ((unsigned)l1 << 16);
        }
        #pragma unroll
        for (int l = 0; l < 6; ++l) {       // W slice [192][32] bf16 pre-T
            int e = t + l * 256;
            int cc = e >> 3, k4 = (e & 7) * 4;
            *(uint2*)&WS_h[cc * 40 + k4] = *(const uint2*)&wt_h[cc * DIM + kt * 32 + k4];
            *(uint2*)&WS_l[cc * 40 + k4] = *(const uint2*)&wt_l[cc * DIM + kt * 32 + k4];
        }
        __syncthreads();

        bf16x8 ah = *(const bf16x8*)&AS_h[(wv * 16 + c) * 40 + q * 8];
        bf16x8 al = *(const bf16x8*)&AS_l[(wv * 16 + c) * 40 + q * 8];
        #pragma unroll
        for (int nt = 0; nt < 12; ++nt) {
            bf16x8 bh = *(const bf16x8*)&WS_h[(nt * 16 + c) * 40 + q * 8];
            bf16x8 bl = *(const bf16x8*)&WS_l[(nt * 16 + c) * 40 + q * 8];
            acc[nt] = mfma16(ah, bh, acc[nt]);
            acc[nt] = mfma16(al, bh, acc[nt]);
            acc[nt] = mfma16(ah, bl, acc[nt]);
        }
    }
    __syncthreads();   // all reads of io done before writes below (in-place)

    #pragma unroll
    for (int nt = 0; nt < 12; ++nt) {
        int col = nt * 16 + c;
        float bo = b_out[col];
        #pragma unroll
        for (int r = 0; r < 4; ++r)
            io[(row0 + wv * 16 + q * 4 + r) * DIM + col] = acc[nt][r] + bo;
    }
}

// ===========================================================================
// Fallback (round-1 fp32 kernels) when ws_size is too small
// ===========================================================================
__global__ __launch_bounds__(256, 2)
void attn_kernel(const float* __restrict__ x, const int* __restrict__ mask,
                 const int* __restrict__ rel_index, const float* __restrict__ w_qkv,
                 const float* __restrict__ b_qkv, const float* __restrict__ bias_table,
                 float* __restrict__ out)
{
    __shared__ float smem[19136];
    float* xt = smem;
    float* wt = smem + 4768;
    float* qs = smem;
    float* ks = smem + 4752;
    float* vs = smem + 9504;
    float* S  = smem + 14400;

    const int t  = threadIdx.x;
    const int w  = blockIdx.x / NH;
    const int h  = blockIdx.x % NH;
    const int tx = t & 15;
    const int ty = t >> 4;
    const float scale = 0.17677669529663687f;
    const float* xg = x + (size_t)w * NT * DIM;

    float acc[9][6];
    #pragma unroll
    for (int i = 0; i < 9; ++i)
        #pragma unroll
        for (int j = 0; j < 6; ++j) acc[i][j] = 0.f;

    for (int kt = 0; kt < 6; ++kt) {
        #pragma unroll
        for (int l = 0; l < 18; ++l) {
            int e = t + l * 256;
            int n = e >> 5, kk = e & 31;
            xt[kk * 149 + n] = xg[n * DIM + kt * 32 + kk];
        }
        #pragma unroll
        for (int l = 0; l < 12; ++l) {
            int e = t + l * 256;
            int kk = e / 96, cc = e - kk * 96;
            int col = (cc >> 5) * DIM + h * HD + (cc & 31);
            wt[kk * 96 + cc] = w_qkv[(kt * 32 + kk) * WCOLS + col];
        }
        __syncthreads();
        #pragma unroll
        for (int kk = 0; kk < 32; ++kk) {
            float a[9], b[6];
            #pragma unroll
            for (int i = 0; i < 9; ++i) a[i] = xt[kk * 149 + ty * 9 + i];
            #pragma unroll
            for (int j = 0; j < 6; ++j) b[j] = wt[kk * 96 + tx * 6 + j];
            #pragma unroll
            for (int i = 0; i < 9; ++i)
                #pragma unroll
                for (int j = 0; j < 6; ++j) acc[i][j] = fmaf(a[i], b[j], acc[i][j]);
        }
        __syncthreads();
    }

    #pragma unroll
    for (int j = 0; j < 6; ++j) {
        int cc = tx * 6 + j;
        int part = cc >> 5, jj = cc & 31;
        float bq = b_qkv[part * DIM + h * HD + jj];
        #pragma unroll
        for (int i = 0; i < 9; ++i) {
            int r = ty * 9 + i;
            float val = acc[i][j] + bq;
            if (part == 0)      qs[r * 33 + jj] = val * scale;
            else if (part == 1) ks[r * 33 + jj] = val;
            else                vs[r * 34 + jj] = val;
        }
    }
    __syncthreads();

    const int wave = t >> 6, lane = t & 63;
    for (int rt = 0; rt < 5; ++rt) {
        const int rows = (rt == 4) ? 16 : 32;
        {
            int r0 = ty * 2;
            int n0 = rt * 32 + r0; if (n0 > NT - 1) n0 = NT - 1;
            int n1 = n0 + 1;       if (n1 > NT - 1) n1 = NT - 1;
            int m0 = tx * 9;
            float s0[9], s1[9];
            #pragma unroll
            for (int j = 0; j < 9; ++j) { s0[j] = 0.f; s1[j] = 0.f; }
            #pragma unroll
            for (int kk = 0; kk < 32; ++kk) {
                float a0 = qs[n0 * 33 + kk];
                float a1 = qs[n1 * 33 + kk];
                #pragma unroll
                for (int j = 0; j < 9; ++j) {
                    float bk = ks[(m0 + j) * 33 + kk];
                    s0[j] = fmaf(a0, bk, s0[j]);
                    s1[j] = fmaf(a1, bk, s1[j]);
                }
            }
            if (r0 < rows) {
                #pragma unroll
                for (int j = 0; j < 9; ++j) S[r0 * 148 + m0 + j] = s0[j];
                #pragma unroll
                for (int j = 0; j < 9; ++j) S[(r0 + 1) * 148 + m0 + j] = s1[j];
            }
        }
        __syncthreads();

        for (int r = wave; r < rows; r += 4) {
            int n = rt * 32 + r;
            const int* mrow = mask + ((size_t)w * NT + n) * NT;
            const int* rrow = rel_index + n * NT;
            float e0 = S[r * 148 + lane] + bias_table[rrow[lane] * NH + h];
            if (mrow[lane] == 0) e0 = -1e9f;
            float e1 = S[r * 148 + 64 + lane] + bias_table[rrow[64 + lane] * NH + h];
            if (mrow[64 + lane] == 0) e1 = -1e9f;
            float e2 = -INFINITY;
            if (lane < 16) {
                e2 = S[r * 148 + 128 + lane] + bias_table[rrow[128 + lane] * NH + h];
                if (mrow[128 + lane] == 0) e2 = -1e9f;
            }
            float vmax = fmaxf(fmaxf(e0, e1), e2);
            #pragma unroll
            for (int off = 32; off > 0; off >>= 1)
                vmax = fmaxf(vmax, __shfl_xor(vmax, off, 64));
            float p0 = __expf(e0 - vmax);
            float p1 = __expf(e1 - vmax);
            float p2 = (lane < 16) ? __expf(e2 - vmax) : 0.f;
            float s = p0 + p1 + p2;
            #pragma unroll
            for (int off = 32; off > 0; off >>= 1)
                s += __shfl_xor(s, off, 64);
            float rinv = 1.f / s;
            S[r * 148 + lane] = p0 * rinv;
            S[r * 148 + 64 + lane] = p1 * rinv;
            if (lane < 16) S[r * 148 + 128 + lane] = p2 * rinv;
        }
        __syncthreads();

        {
            int r0 = ty * 2, dd0 = tx * 2;
            if (r0 < rows) {
                float o00 = 0, o01 = 0, o10 = 0, o11 = 0;
                #pragma unroll
                for (int m = 0; m < NT; ++m) {
                    float p0 = S[r0 * 148 + m];
                    float p1 = S[(r0 + 1) * 148 + m];
                    float2 vv = *(const float2*)&vs[m * 34 + dd0];
                    o00 = fmaf(p0, vv.x, o00);
                    o01 = fmaf(p0, vv.y, o01);
                    o10 = fmaf(p1, vv.x, o10);
                    o11 = fmaf(p1, vv.y, o11);
                }
                int n0 = rt * 32 + r0;
                *(float2*)&out[((size_t)(w * NT + n0)) * DIM + h * HD + dd0] = make_float2(o00, o01);
                *(float2*)&out[((size_t)(w * NT + n0 + 1)) * DIM + h * HD + dd0] = make_float2(o10, o11);
            }
        }
        __syncthreads();
    }
}

__global__ __launch_bounds__(256, 2)
void proj_kernel(float* __restrict__ io, const float* __restrict__ w_out,
                 const float* __restrict__ b_out)
{
    __shared__ float in_t[64 * 196];
    __shared__ float wt[32 * 192];
    const int t = threadIdx.x;
    const size_t row0 = (size_t)blockIdx.x * 64;

    #pragma unroll
    for (int l = 0; l < 12; ++l) {
        int e = t + l * 256;
        int r = e / 48, c4 = e - r * 48;
        float4 val = *(const float4*)&io[(row0 + r) * DIM + c4 * 4];
        *(float4*)&in_t[r * 196 + c4 * 4] = val;
    }
    const int tx = t & 15, ty = t >> 4;
    float acc[4][12];
    #pragma unroll
    for (int i = 0; i < 4; ++i)
        #pragma unroll
        for (int j = 0; j < 12; ++j) acc[i][j] = 0.f;

    for (int kt = 0; kt < 6; ++kt) {
        __syncthreads();
        #pragma unroll
        for (int l = 0; l < 6; ++l) {
            int e = t + l * 256;
            int kk = e / 48, c4 = e - kk * 48;
            *(float4*)&wt[kk * 192 + c4 * 4] =
                *(const float4*)&w_out[(kt * 32 + kk) * DIM + c4 * 4];
        }
        __syncthreads();
        #pragma unroll
        for (int kk = 0; kk < 32; ++kk) {
            float a[4];
            #pragma unroll
            for (int i = 0; i < 4; ++i) a[i] = in_t[(ty * 4 + i) * 196 + kt * 32 + kk];
            float b[12];
            #pragma unroll
            for (int j4 = 0; j4 < 3; ++j4) {
                float4 bb = *(const float4*)&wt[kk * 192 + tx * 12 + j4 * 4];
                b[j4 * 4] = bb.x; b[j4 * 4 + 1] = bb.y;
                b[j4 * 4 + 2] = bb.z; b[j4 * 4 + 3] = bb.w;
            }
            #pragma unroll
            for (int i = 0; i < 4; ++i)
                #pragma unroll
                for (int j = 0; j < 12; ++j)
                    acc[i][j] = fmaf(a[i], b[j], acc[i][j]);
        }
    }

    float bo[12];
    #pragma unroll
    for (int j4 = 0; j4 < 3; ++j4) {
        float4 bb = *(const float4*)&b_out[tx * 12 + j4 * 4];
        bo[j4 * 4] = bb.x; bo[j4 * 4 + 1] = bb.y;
        bo[j4 * 4 + 2] = bb.z; bo[j4 * 4 + 3] = bb.w;
    }
    #pragma unroll
    for (int i = 0; i < 4; ++i) {
        size_t r = row0 + ty * 4 + i;
        #pragma unroll
        for (int j4 = 0; j4 < 3; ++j4) {
            float4 o;
            o.x = acc[i][j4 * 4]     + bo[j4 * 4];
            o.y = acc[i][j4 * 4 + 1] + bo[j4 * 4 + 1];
            o.z = acc[i][j4 * 4 + 2] + bo[j4 * 4 + 2];
            o.w = acc[i][j4 * 4 + 3] + bo[j4 * 4 + 3];
            *(float4*)&io[r * DIM + tx * 12 + j4 * 4] = o;
        }
    }
}

// ===========================================================================
extern "C" void kernel_launch(void* const* d_in, const int* in_sizes, int n_in,
                              void* d_out, int out_size, void* d_ws, size_t ws_size,
                              hipStream_t stream) {
    const float* x          = (const float*)d_in[0];
    const int*   mask       = (const int*)d_in[1];
    const int*   rel_index  = (const int*)d_in[2];
    const float* w_qkv      = (const float*)d_in[3];
    const float* b_qkv      = (const float*)d_in[4];
    const float* w_out      = (const float*)d_in[5];
    const float* b_out      = (const float*)d_in[6];
    const float* bias_table = (const float*)d_in[7];
    float* out = (float*)d_out;

    // ws layout (bytes):
    //   bias_pre  [6][144][144] f32 : @0        497664
    //   wqt_h     [6][96][192] bf16 : @497664   221184
    //   wqt_l                       : @718848   221184
    //   wout_h    [192][192]   bf16 : @940032    73728
    //   wout_l                      : @1013760   73728   -> total 1087488
    const size_t WS_NEED = 1087488;

    if (ws_size >= WS_NEED) {
        char* ws = (char*)d_ws;
        float*          bias_pre = (float*)ws;
        unsigned short* wqt_h    = (unsigned short*)(ws + 497664);
        unsigned short* wqt_l    = (unsigned short*)(ws + 718848);
        unsigned short* wout_h   = (unsigned short*)(ws + 940032);
        unsigned short* wout_l   = (unsigned short*)(ws + 1013760);

        hipLaunchKernelGGL(prep_bias, dim3(486), dim3(256), 0, stream,
                           rel_index, bias_table, bias_pre);
        hipLaunchKernelGGL(prep_wqkv, dim3(432), dim3(256), 0, stream,
                           w_qkv, wqt_h, wqt_l);
        hipLaunchKernelGGL(prep_wout, dim3(144), dim3(256), 0, stream,
                           w_out, wout_h, wout_l);
        hipLaunchKernelGGL(attn_mfma, dim3(NW * NH), dim3(192), 0, stream,
                           x, mask, bias_pre, wqt_h, wqt_l, b_qkv, out);
        hipLaunchKernelGGL(proj_mfma, dim3(NW * NT / 64), dim3(256), 0, stream,
                           out, wout_h, wout_l, b_out);
    } else {
        hipLaunchKernelGGL(attn_kernel, dim3(NW * NH), dim3(256), 0, stream,
                           x, mask, rel_index, w_qkv, b_qkv, bias_table, out);
        hipLaunchKernelGGL(proj_kernel, dim3(NW * NT / 64), dim3(256), 0, stream,
                           out, w_out, b_out);
    }
}

// Round 3
// 647.428 us; speedup vs baseline: 2.6722x; 1.1779x over previous
//
#include <hip/hip_runtime.h>
#include <math.h>

#define NW 960
#define NT 144
#define DIM 192
#define NH 6
#define HD 32
#define WCOLS 576

typedef __bf16 bf16x8 __attribute__((ext_vector_type(8)));
typedef float floatx4 __attribute__((ext_vector_type(4)));

__device__ __forceinline__ unsigned short f2bf(float x) {
    union { float f; unsigned u; } v; v.f = x;
    unsigned r = v.u + 0x7fffu + ((v.u >> 16) & 1u);
    return (unsigned short)(r >> 16);
}
__device__ __forceinline__ float bf2f(unsigned short b) {
    union { unsigned u; float f; } v; v.u = ((unsigned)b) << 16;
    return v.f;
}
__device__ __forceinline__ floatx4 mfma16(bf16x8 a, bf16x8 b, floatx4 c) {
    return __builtin_amdgcn_mfma_f32_16x16x32_bf16(a, b, c, 0, 0, 0);
}
__device__ __forceinline__ void gll16(const void* g, void* l) {
    __builtin_amdgcn_global_load_lds(
        (const __attribute__((address_space(1))) unsigned int*)g,
        (__attribute__((address_space(3))) unsigned int*)l, 16, 0, 0);
}

// ===========================================================================
// Tier-1 prep kernels: frag-linear layouts in ws
// ===========================================================================
__global__ void prep_bias(const int* __restrict__ rel_index,
                          const float* __restrict__ bias_table,
                          float* __restrict__ bias_pre) {
    int i = blockIdx.x * 256 + threadIdx.x;           // [6][144][144]
    if (i < NH * NT * NT) {
        int h = i / (NT * NT);
        int rem = i - h * (NT * NT);
        bias_pre[i] = bias_table[rel_index[rem] * NH + h];
    }
}

// mbits[w][n][5] : bit j of word wi = (mask[w][n][wi*32+j] != 0)
__global__ void prep_mask(const int* __restrict__ mask, unsigned* __restrict__ mbits) {
    int i = blockIdx.x * 256 + threadIdx.x;           // 960*144*5
    if (i < NW * NT * 5) {
        int wi = i % 5;
        int row = i / 5;                               // w*144 + n
        const int* mrow = mask + (size_t)row * NT + wi * 32;
        int lim = (wi == 4) ? 16 : 32;
        unsigned b = 0;
        for (int j = 0; j < lim; ++j) b |= (mrow[j] != 0 ? 1u : 0u) << j;
        mbits[i] = b;
    }
}

// wq frag: [h][j(6)][kt(6)][lane(64)][pos(8)] ; element = w_qkv col-slice of head h
__global__ void prep_wq_frag(const float* __restrict__ w_qkv,
                             unsigned short* __restrict__ wh,
                             unsigned short* __restrict__ wl) {
    int i = blockIdx.x * 256 + threadIdx.x;           // 6*6*6*512 = 110592
    if (i < NH * 6 * 6 * 512) {
        int h = i / 18432; int r = i - h * 18432;
        int j = r / 3072;  r -= j * 3072;
        int kt = r / 512;  r -= kt * 512;
        int lane = r >> 3, pos = r & 7;
        int col96 = j * 16 + (lane & 15);
        int k = kt * 32 + (lane >> 4) * 8 + pos;
        float v = w_qkv[k * WCOLS + (col96 >> 5) * DIM + h * HD + (col96 & 31)];
        unsigned short hi = f2bf(v);
        wh[i] = hi;
        wl[i] = f2bf(v - bf2f(hi));
    }
}

// wout frag: [nt(12)][kt(6)][lane(64)][pos(8)]
__global__ void prep_wo_frag(const float* __restrict__ w_out,
                             unsigned short* __restrict__ wh,
                             unsigned short* __restrict__ wl) {
    int i = blockIdx.x * 256 + threadIdx.x;           // 12*6*512 = 36864
    if (i < 12 * 6 * 512) {
        int nt = i / 3072; int r = i - nt * 3072;
        int kt = r / 512;  r -= kt * 512;
        int lane = r >> 3, pos = r & 7;
        int ocol = nt * 16 + (lane & 15);
        int k = kt * 32 + (lane >> 4) * 8 + pos;
        float v = w_out[k * DIM + ocol];
        unsigned short hi = f2bf(v);
        wh[i] = hi;
        wl[i] = f2bf(v - bf2f(hi));
    }
}

// x frag (bf16, hi only): [w][kt(6)][tile(9)][lane(64)][pos(8)], one u32 per thread
__global__ void prep_x_frag(const float* __restrict__ x, unsigned* __restrict__ xf) {
    int d = blockIdx.x * 256 + threadIdx.x;           // 960*13824 dwords
    int w = d / 13824; int r = d - w * 13824;
    int kt = r / 2304;  r -= kt * 2304;
    int tile = r / 256; r -= tile * 256;
    int lane = r >> 2, pp = r & 3;
    int n = tile * 16 + (lane & 15);
    int k = kt * 32 + (lane >> 4) * 8 + pp * 2;
    float2 xv = *(const float2*)&x[((size_t)w * NT + n) * DIM + k];
    xf[d] = (unsigned)f2bf(xv.x) | ((unsigned)f2bf(xv.y) << 16);
}

// ===========================================================================
// Tier-1 attention. Block = 384 thr (6 waves) per (w,h).
// LDS shorts: Q[9][512]@0, K@4608, Vt[2*5][512]@9216, P[6*5][512]@14336
// XS ping-pong aliases P region: @14336 / @18944. Total 29696 sh = 59392 B.
// ===========================================================================
__global__ __launch_bounds__(384, 3)
void attn2(const unsigned* __restrict__ mbits, const float* __restrict__ bias_pre,
           const unsigned short* __restrict__ xf,
           const unsigned short* __restrict__ wqh, const unsigned short* __restrict__ wql,
           const float* __restrict__ b_qkv, float* __restrict__ out)
{
    __shared__ __align__(16) unsigned short lds[29696];
    const int QO = 0, KO = 4608, VtO = 9216, PO = 14336;
    const int XS0 = 14336, XS1 = 18944;

    const int t = threadIdx.x;
    const int w = blockIdx.x / NH;
    const int h = blockIdx.x % NH;
    const int lane = t & 63, wv = t >> 6;
    const int c = lane & 15, q = lane >> 4;
    const float scale = 0.17677669529663687f;

    // hoisted W hi frags; lo loaded per-kt
    const unsigned short* wqhf = wqh + (size_t)((h * 6 + wv) * 6) * 512 + lane * 8;
    const unsigned short* wqlf = wql + (size_t)((h * 6 + wv) * 6) * 512 + lane * 8;
    bf16x8 bh[6];
    #pragma unroll
    for (int kt = 0; kt < 6; ++kt) bh[kt] = *(const bf16x8*)&wqhf[kt * 512];

    const unsigned short* xw = xf + (size_t)w * 6 * 9 * 512;

    floatx4 acc[9];
    #pragma unroll
    for (int i = 0; i < 9; ++i) acc[i] = (floatx4)0.0f;

    // prefetch kt=0 X tiles into XS0
    for (int tl = wv; tl < 9; tl += 6)
        gll16(&xw[(size_t)tl * 512 + lane * 8], &lds[XS0 + tl * 512 + lane * 8]);
    __syncthreads();

    #pragma unroll
    for (int kt = 0; kt < 6; ++kt) {
        const unsigned short* Xc = &lds[(kt & 1) ? XS1 : XS0];
        if (kt < 5) {
            unsigned short* Xn = &lds[(kt & 1) ? XS0 : XS1];
            for (int tl = wv; tl < 9; tl += 6)
                gll16(&xw[(size_t)((kt + 1) * 9 + tl) * 512 + lane * 8],
                      &Xn[tl * 512 + lane * 8]);
        }
        bf16x8 bl = *(const bf16x8*)&wqlf[kt * 512];
        #pragma unroll
        for (int i = 0; i < 9; ++i) {
            bf16x8 ah = *(const bf16x8*)&Xc[i * 512 + lane * 8];
            acc[i] = mfma16(ah, bh[kt], acc[i]);
            acc[i] = mfma16(ah, bl, acc[i]);
        }
        __syncthreads();
    }

    // ---- transition: scatter acc -> Q / K / Vt frag layouts + zero pads ----
    {
        const int part = wv >> 1;
        const int kk = ((wv & 1) << 4) + c;          // col within 32-wide part
        const float bq = b_qkv[part * DIM + h * HD + kk];
        if (part == 0) {
            #pragma unroll
            for (int i = 0; i < 9; ++i)
                #pragma unroll
                for (int r = 0; r < 4; ++r)
                    lds[QO + i * 512 + ((q * 4 + r) + 16 * (kk >> 3)) * 8 + (kk & 7)] =
                        f2bf((acc[i][r] + bq) * scale);
        } else if (part == 1) {
            #pragma unroll
            for (int i = 0; i < 9; ++i)
                #pragma unroll
                for (int r = 0; r < 4; ++r)
                    lds[KO + i * 512 + ((q * 4 + r) + 16 * (kk >> 3)) * 8 + (kk & 7)] =
                        f2bf(acc[i][r] + bq);
        } else {
            #pragma unroll
            for (int i = 0; i < 9; ++i)
                #pragma unroll
                for (int r = 0; r < 4; ++r) {
                    int n = i * 16 + q * 4 + r;
                    lds[VtO + ((wv & 1) * 5 + (n >> 5)) * 512 +
                        (c + 16 * ((n >> 3) & 3)) * 8 + (n & 7)] = f2bf(acc[i][r] + bq);
                }
        }
        // zero pads: Vt tok 144..159 (512 sh) + P k 144..159 (1536 sh)
        for (int e = t; e < 2048; e += 384) {
            if (e < 512) {
                int ntv = e >> 8, l2 = 32 + ((e >> 3) & 31);
                lds[VtO + (ntv * 5 + 4) * 512 + l2 * 8 + (e & 7)] = 0;
            } else {
                int e3 = e - 512;
                int slab = e3 >> 8, l2 = 32 + ((e3 >> 3) & 31);
                lds[PO + (slab * 5 + 4) * 512 + l2 * 8 + (e3 & 7)] = 0;
            }
        }
    }
    __syncthreads();

    // ---- Phase B: barrier-free, strips round-robin over waves ----
    for (int s = wv; s < 9; s += 6) {
        bf16x8 qf = *(const bf16x8*)&lds[QO + s * 512 + lane * 8];
        floatx4 sacc[9];
        #pragma unroll
        for (int nt = 0; nt < 9; ++nt) {
            bf16x8 kf = *(const bf16x8*)&lds[KO + nt * 512 + lane * 8];
            sacc[nt] = mfma16(qf, kf, (floatx4)0.0f);
        }

        #pragma unroll
        for (int r = 0; r < 4; ++r) {
            int n = s * 16 + q * 4 + r;
            const float* brow = bias_pre + h * (NT * NT) + n * NT;
            const unsigned* mb = mbits + ((size_t)w * NT + n) * 5;
            float e[9]; float mx = -1e30f;
            #pragma unroll
            for (int nt = 0; nt < 9; ++nt) {
                float val = sacc[nt][r] + brow[nt * 16 + c];
                unsigned bit = (mb[nt >> 1] >> (((nt & 1) << 4) + c)) & 1u;
                val = bit ? val : -1e9f;
                e[nt] = val;
                mx = fmaxf(mx, val);
            }
            #pragma unroll
            for (int o = 8; o; o >>= 1) mx = fmaxf(mx, __shfl_xor(mx, o, 64));
            float sum = 0.f;
            #pragma unroll
            for (int nt = 0; nt < 9; ++nt) { e[nt] = __expf(e[nt] - mx); sum += e[nt]; }
            #pragma unroll
            for (int o = 8; o; o >>= 1) sum += __shfl_xor(sum, o, 64);
            float rinv = 1.0f / sum;
            #pragma unroll
            for (int nt = 0; nt < 9; ++nt) {
                int col = nt * 16 + c;
                lds[PO + (wv * 5 + (col >> 5)) * 512 +
                    ((q * 4 + r) + 16 * ((col >> 3) & 3)) * 8 + (col & 7)] =
                    f2bf(e[nt] * rinv);
            }
        }

        floatx4 oacc[2];
        oacc[0] = (floatx4)0.0f; oacc[1] = (floatx4)0.0f;
        #pragma unroll
        for (int kt5 = 0; kt5 < 5; ++kt5) {
            bf16x8 pf = *(const bf16x8*)&lds[PO + (wv * 5 + kt5) * 512 + lane * 8];
            #pragma unroll
            for (int ntv = 0; ntv < 2; ++ntv) {
                bf16x8 vf = *(const bf16x8*)&lds[VtO + (ntv * 5 + kt5) * 512 + lane * 8];
                oacc[ntv] = mfma16(pf, vf, oacc[ntv]);
            }
        }
        #pragma unroll
        for (int r = 0; r < 4; ++r) {
            int n = s * 16 + q * 4 + r;
            float* orow = out + ((size_t)(w * NT + n)) * DIM + h * HD;
            orow[c] = oacc[0][r];
            orow[16 + c] = oacc[1][r];
        }
    }
}

// ===========================================================================
// Tier-1 out-proj: no LDS, no barriers, in-place. 256 thr, wave owns 16 rows.
// ===========================================================================
__global__ __launch_bounds__(256, 4)
void proj2(float* __restrict__ io,
           const unsigned short* __restrict__ wh, const unsigned short* __restrict__ wl,
           const float* __restrict__ b_out)
{
    const int t = threadIdx.x;
    const int lane = t & 63, wv = t >> 6;
    const int c = lane & 15, q = lane >> 4;
    const size_t row = (size_t)blockIdx.x * 64 + wv * 16 + c;

    floatx4 acc[12];
    #pragma unroll
    for (int j = 0; j < 12; ++j) acc[j] = (floatx4)0.0f;

    const unsigned short* whf = wh + lane * 8;
    const unsigned short* wlf = wl + lane * 8;

    #pragma unroll
    for (int kt = 0; kt < 6; ++kt) {
        const float4* ap = (const float4*)&io[row * DIM + kt * 32 + q * 8];
        float4 a0 = ap[0], a1 = ap[1];
        union { bf16x8 v; unsigned short s[8]; } ua;
        ua.s[0] = f2bf(a0.x); ua.s[1] = f2bf(a0.y);
        ua.s[2] = f2bf(a0.z); ua.s[3] = f2bf(a0.w);
        ua.s[4] = f2bf(a1.x); ua.s[5] = f2bf(a1.y);
        ua.s[6] = f2bf(a1.z); ua.s[7] = f2bf(a1.w);
        #pragma unroll
        for (int nt = 0; nt < 12; ++nt) {
            bf16x8 bh = *(const bf16x8*)&whf[(nt * 6 + kt) * 512];
            bf16x8 bl = *(const bf16x8*)&wlf[(nt * 6 + kt) * 512];
            acc[nt] = mfma16(ua.v, bh, acc[nt]);
            acc[nt] = mfma16(ua.v, bl, acc[nt]);
        }
    }
    // all reads of this wave's rows are done; writes hit the same 16-row slab
    const size_t row0 = (size_t)blockIdx.x * 64 + wv * 16;
    #pragma unroll
    for (int nt = 0; nt < 12; ++nt) {
        int col = nt * 16 + c;
        float bo = b_out[col];
        #pragma unroll
        for (int r = 0; r < 4; ++r)
            io[(row0 + q * 4 + r) * DIM + col] = acc[nt][r] + bo;
    }
}

// ===========================================================================
// Tier-2 fallback (R2 kernels, need only 1.09 MB ws)
// ===========================================================================
__global__ void prep_wqkv(const float* __restrict__ w_qkv,
                          unsigned short* __restrict__ wqt_h,
                          unsigned short* __restrict__ wqt_l) {
    int i = blockIdx.x * 256 + threadIdx.x;
    if (i < NH * 96 * DIM) {
        int h = i / (96 * DIM);
        int rem = i - h * (96 * DIM);
        int c = rem / DIM, k = rem - c * DIM;
        float v = w_qkv[k * WCOLS + (c >> 5) * DIM + h * HD + (c & 31)];
        unsigned short hi = f2bf(v);
        wqt_h[i] = hi;
        wqt_l[i] = f2bf(v - bf2f(hi));
    }
}

__global__ void prep_wout(const float* __restrict__ w_out,
                          unsigned short* __restrict__ wt_h,
                          unsigned short* __restrict__ wt_l) {
    int i = blockIdx.x * 256 + threadIdx.x;
    if (i < DIM * DIM) {
        int c = i / DIM, k = i - c * DIM;
        float v = w_out[k * DIM + c];
        unsigned short hi = f2bf(v);
        wt_h[i] = hi;
        wt_l[i] = f2bf(v - bf2f(hi));
    }
}

__global__ __launch_bounds__(192, 2)
void attn_mfma(const float* __restrict__ x, const int* __restrict__ mask,
               const float* __restrict__ bias_pre,
               const unsigned short* __restrict__ wqt_h,
               const unsigned short* __restrict__ wqt_l,
               const float* __restrict__ b_qkv, float* __restrict__ out)
{
    __shared__ __align__(16) unsigned short lds[26496];
    unsigned short* XS_h = lds;
    unsigned short* XS_l = lds + 5760;
    unsigned short* WS_h = lds + 11520;
    unsigned short* WS_l = lds + 15360;
    unsigned short* Q  = lds;
    unsigned short* K  = lds + 5760;
    unsigned short* Vt = lds + 11520;
    unsigned short* P  = lds + 19200;

    const int t = threadIdx.x;
    const int w = blockIdx.x / NH;
    const int h = blockIdx.x % NH;
    const int lane = t & 63, wv = t >> 6;
    const int c = lane & 15, q = lane >> 4;
    const float scale = 0.17677669529663687f;

    const float* xg = x + (size_t)w * NT * DIM;
    const unsigned short* wqh = wqt_h + h * 96 * DIM;
    const unsigned short* wql = wqt_l + h * 96 * DIM;

    floatx4 acc[3][6];
    #pragma unroll
    for (int i = 0; i < 3; ++i)
        #pragma unroll
        for (int j = 0; j < 6; ++j) acc[i][j] = (floatx4)0.0f;

    for (int kt = 0; kt < 6; ++kt) {
        __syncthreads();
        #pragma unroll
        for (int l = 0; l < 12; ++l) {
            int e = t + l * 192;
            int n = e >> 4, kk2 = (e & 15) * 2;
            float2 xv = *(const float2*)&xg[n * DIM + kt * 32 + kk2];
            unsigned short h0 = f2bf(xv.x), h1 = f2bf(xv.y);
            unsigned short l0 = f2bf(xv.x - bf2f(h0)), l1 = f2bf(xv.y - bf2f(h1));
            *(unsigned*)&XS_h[n * 40 + kk2] = (unsigned)h0 | ((unsigned)h1 << 16);
            *(unsigned*)&XS_l[n * 40 + kk2] = (unsigned)l0 | ((unsigned)l1 << 16);
        }
        #pragma unroll
        for (int l = 0; l < 4; ++l) {
            int e = t + l * 192;
            int cc = e >> 3, k4 = (e & 7) * 4;
            *(uint2*)&WS_h[cc * 40 + k4] = *(const uint2*)&wqh[cc * DIM + kt * 32 + k4];
            *(uint2*)&WS_l[cc * 40 + k4] = *(const uint2*)&wql[cc * DIM + kt * 32 + k4];
        }
        __syncthreads();

        bf16x8 ah[3], al[3];
        #pragma unroll
        for (int i = 0; i < 3; ++i) {
            int row = (3 * wv + i) * 16 + c;
            ah[i] = *(const bf16x8*)&XS_h[row * 40 + q * 8];
            al[i] = *(const bf16x8*)&XS_l[row * 40 + q * 8];
        }
        #pragma unroll
        for (int j = 0; j < 6; ++j) {
            int cr = j * 16 + c;
            bf16x8 bh2 = *(const bf16x8*)&WS_h[cr * 40 + q * 8];
            bf16x8 bl2 = *(const bf16x8*)&WS_l[cr * 40 + q * 8];
            #pragma unroll
            for (int i = 0; i < 3; ++i) {
                acc[i][j] = mfma16(ah[i], bh2, acc[i][j]);
                acc[i][j] = mfma16(al[i], bh2, acc[i][j]);
                acc[i][j] = mfma16(ah[i], bl2, acc[i][j]);
            }
        }
    }
    __syncthreads();

    #pragma unroll
    for (int j = 0; j < 6; ++j) {
        int part = j >> 1, jj = (j & 1) * 16 + c;
        float bq = b_qkv[part * DIM + h * HD + jj];
        #pragma unroll
        for (int i = 0; i < 3; ++i) {
            int mt = 3 * wv + i;
            #pragma unroll
            for (int r = 0; r < 4; ++r) {
                int n = mt * 16 + q * 4 + r;
                float v = acc[i][j][r] + bq;
                if (part == 0)      Q[n * 40 + jj] = f2bf(v * scale);
                else if (part == 1) K[n * 40 + jj] = f2bf(v);
                else                Vt[jj * 152 + n] = f2bf(v);
            }
        }
    }
    __syncthreads();

    for (int it = 0; it < 3; ++it) {
        int s = wv + 3 * it;
        int n0 = s * 16;

        bf16x8 qf = *(const bf16x8*)&Q[(n0 + c) * 40 + q * 8];
        floatx4 sacc[9];
        #pragma unroll
        for (int nt = 0; nt < 9; ++nt) {
            bf16x8 kf = *(const bf16x8*)&K[(nt * 16 + c) * 40 + q * 8];
            sacc[nt] = mfma16(qf, kf, (floatx4)0.0f);
        }

        #pragma unroll
        for (int r = 0; r < 4; ++r) {
            int n = n0 + q * 4 + r;
            const float* brow = bias_pre + h * (NT * NT) + n * NT;
            const int* mrow = mask + ((size_t)w * NT + n) * NT;
            float e[9]; float mx = -1e30f;
            #pragma unroll
            for (int nt = 0; nt < 9; ++nt) {
                int m = nt * 16 + c;
                float val = sacc[nt][r] + brow[m];
                if (mrow[m] == 0) val = -1e9f;
                e[nt] = val;
                mx = fmaxf(mx, val);
            }
            #pragma unroll
            for (int o = 8; o; o >>= 1) mx = fmaxf(mx, __shfl_xor(mx, o, 64));
            float sum = 0.f;
            #pragma unroll
            for (int nt = 0; nt < 9; ++nt) { e[nt] = __expf(e[nt] - mx); sum += e[nt]; }
            #pragma unroll
            for (int o = 8; o; o >>= 1) sum += __shfl_xor(sum, o, 64);
            float rinv = 1.0f / sum;
            #pragma unroll
            for (int nt = 0; nt < 9; ++nt)
                P[(wv * 16 + q * 4 + r) * 152 + nt * 16 + c] = f2bf(e[nt] * rinv);
        }

        floatx4 oacc[2];
        oacc[0] = (floatx4)0.0f; oacc[1] = (floatx4)0.0f;
        #pragma unroll
        for (int kt5 = 0; kt5 < 5; ++kt5) {
            int kb = (kt5 < 4) ? kt5 * 32 : 112;
            bf16x8 pf;
            if (kt5 == 4 && q < 2) pf = (bf16x8)(__bf16)0.0f;
            else pf = *(const bf16x8*)&P[(wv * 16 + c) * 152 + kb + q * 8];
            #pragma unroll
            for (int ntv = 0; ntv < 2; ++ntv) {
                bf16x8 vf = *(const bf16x8*)&Vt[(ntv * 16 + c) * 152 + kb + q * 8];
                oacc[ntv] = mfma16(pf, vf, oacc[ntv]);
            }
        }
        #pragma unroll
        for (int r = 0; r < 4; ++r) {
            int n = n0 + q * 4 + r;
            float* orow = out + ((size_t)(w * NT + n)) * DIM + h * HD;
            orow[c] = oacc[0][r];
            orow[16 + c] = oacc[1][r];
        }
    }
}

__global__ __launch_bounds__(256, 3)
void proj_mfma(float* __restrict__ io,
               const unsigned short* __restrict__ wt_h,
               const unsigned short* __restrict__ wt_l,
               const float* __restrict__ b_out)
{
    __shared__ __align__(16) unsigned short lds[20480];
    unsigned short* AS_h = lds;
    unsigned short* AS_l = lds + 2560;
    unsigned short* WS_h = lds + 5120;
    unsigned short* WS_l = lds + 12800;

    const int t = threadIdx.x;
    const int lane = t & 63, wv = t >> 6;
    const int c = lane & 15, q = lane >> 4;
    const size_t row0 = (size_t)blockIdx.x * 64;

    floatx4 acc[12];
    #pragma unroll
    for (int j = 0; j < 12; ++j) acc[j] = (floatx4)0.0f;

    for (int kt = 0; kt < 6; ++kt) {
        __syncthreads();
        #pragma unroll
        for (int l = 0; l < 4; ++l) {
            int e = t + l * 256;
            int r = e >> 4, kk2 = (e & 15) * 2;
            float2 av = *(const float2*)&io[(row0 + r) * DIM + kt * 32 + kk2];
            unsigned short h0 = f2bf(av.x), h1 = f2bf(av.y);
            unsigned short l0 = f2bf(av.x - bf2f(h0)), l1 = f2bf(av.y - bf2f(h1));
            *(unsigned*)&AS_h[r * 40 + kk2] = (unsigned)h0 | ((unsigned)h1 << 16);
            *(unsigned*)&AS_l[r * 40 + kk2] = (unsigned)l0 | ((unsigned)l1 << 16);
        }
        #pragma unroll
        for (int l = 0; l < 6; ++l) {
            int e = t + l * 256;
            int cc = e >> 3, k4 = (e & 7) * 4;
            *(uint2*)&WS_h[cc * 40 + k4] = *(const uint2*)&wt_h[cc * DIM + kt * 32 + k4];
            *(uint2*)&WS_l[cc * 40 + k4] = *(const uint2*)&wt_l[cc * DIM + kt * 32 + k4];
        }
        __syncthreads();

        bf16x8 ah = *(const bf16x8*)&AS_h[(wv * 16 + c) * 40 + q * 8];
        bf16x8 al = *(const bf16x8*)&AS_l[(wv * 16 + c) * 40 + q * 8];
        #pragma unroll
        for (int nt = 0; nt < 12; ++nt) {
            bf16x8 bh2 = *(const bf16x8*)&WS_h[(nt * 16 + c) * 40 + q * 8];
            bf16x8 bl2 = *(const bf16x8*)&WS_l[(nt * 16 + c) * 40 + q * 8];
            acc[nt] = mfma16(ah, bh2, acc[nt]);
            acc[nt] = mfma16(al, bh2, acc[nt]);
            acc[nt] = mfma16(ah, bl2, acc[nt]);
        }
    }
    __syncthreads();

    #pragma unroll
    for (int nt = 0; nt < 12; ++nt) {
        int col = nt * 16 + c;
        float bo = b_out[col];
        #pragma unroll
        for (int r = 0; r < 4; ++r)
            io[(row0 + wv * 16 + q * 4 + r) * DIM + col] = acc[nt][r] + bo;
    }
}

// ===========================================================================
extern "C" void kernel_launch(void* const* d_in, const int* in_sizes, int n_in,
                              void* d_out, int out_size, void* d_ws, size_t ws_size,
                              hipStream_t stream) {
    const float* x          = (const float*)d_in[0];
    const int*   mask       = (const int*)d_in[1];
    const int*   rel_index  = (const int*)d_in[2];
    const float* w_qkv      = (const float*)d_in[3];
    const float* b_qkv      = (const float*)d_in[4];
    const float* w_out      = (const float*)d_in[5];
    const float* b_out      = (const float*)d_in[6];
    const float* bias_table = (const float*)d_in[7];
    float* out = (float*)d_out;

    // Tier-1 ws layout (bytes):
    //   bias_pre @0        : 497664
    //   wq_h     @497664   : 221184   (frag layout)
    //   wq_l     @718848   : 221184
    //   wo_h     @940032   :  73728   (frag layout)
    //   wo_l     @1013760  :  73728
    //   mbits    @1087488  : 2764800
    //   x_frag   @3852288  : 53084160 -> total 56936448
    const size_t WS_BIG = 56936448;

    if (ws_size >= WS_BIG) {
        char* ws = (char*)d_ws;
        float*          bias_pre = (float*)ws;
        unsigned short* wq_h     = (unsigned short*)(ws + 497664);
        unsigned short* wq_l     = (unsigned short*)(ws + 718848);
        unsigned short* wo_h     = (unsigned short*)(ws + 940032);
        unsigned short* wo_l     = (unsigned short*)(ws + 1013760);
        unsigned*       mbits    = (unsigned*)(ws + 1087488);
        unsigned short* x_frag   = (unsigned short*)(ws + 3852288);

        hipLaunchKernelGGL(prep_bias, dim3(486), dim3(256), 0, stream,
                           rel_index, bias_table, bias_pre);
        hipLaunchKernelGGL(prep_mask, dim3(2700), dim3(256), 0, stream, mask, mbits);
        hipLaunchKernelGGL(prep_wq_frag, dim3(432), dim3(256), 0, stream,
                           w_qkv, wq_h, wq_l);
        hipLaunchKernelGGL(prep_wo_frag, dim3(144), dim3(256), 0, stream,
                           w_out, wo_h, wo_l);
        hipLaunchKernelGGL(prep_x_frag, dim3(51840), dim3(256), 0, stream,
                           x, (unsigned*)x_frag);
        hipLaunchKernelGGL(attn2, dim3(NW * NH), dim3(384), 0, stream,
                           mbits, bias_pre, x_frag, wq_h, wq_l, b_qkv, out);
        hipLaunchKernelGGL(proj2, dim3(NW * NT / 64), dim3(256), 0, stream,
                           out, wo_h, wo_l, b_out);
    } else {
        char* ws = (char*)d_ws;
        float*          bias_pre = (float*)ws;
        unsigned short* wqt_h    = (unsigned short*)(ws + 497664);
        unsigned short* wqt_l    = (unsigned short*)(ws + 718848);
        unsigned short* wout_h   = (unsigned short*)(ws + 940032);
        unsigned short* wout_l   = (unsigned short*)(ws + 1013760);

        hipLaunchKernelGGL(prep_bias, dim3(486), dim3(256), 0, stream,
                           rel_index, bias_table, bias_pre);
        hipLaunchKernelGGL(prep_wqkv, dim3(432), dim3(256), 0, stream,
                           w_qkv, wqt_h, wqt_l);
        hipLaunchKernelGGL(prep_wout, dim3(144), dim3(256), 0, stream,
                           w_out, wout_h, wout_l);
        hipLaunchKernelGGL(attn_mfma, dim3(NW * NH), dim3(192), 0, stream,
                           x, mask, bias_pre, wqt_h, wqt_l, b_qkv, out);
        hipLaunchKernelGGL(proj_mfma, dim3(NW * NT / 64), dim3(256), 0, stream,
                           out, wout_h, wout_l, b_out);
    }
}

// Round 4
// 572.005 us; speedup vs baseline: 3.0245x; 1.1319x over previous
//
#include <hip/hip_runtime.h>
#include <math.h>

#define NW 960
#define NT 144
#define DIM 192
#define NH 6
#define HD 32
#define WCOLS 576

typedef __bf16 bf16x8 __attribute__((ext_vector_type(8)));
typedef float floatx4 __attribute__((ext_vector_type(4)));

__device__ __forceinline__ unsigned short f2bf(float x) {
    union { float f; unsigned u; } v; v.f = x;
    unsigned r = v.u + 0x7fffu + ((v.u >> 16) & 1u);
    return (unsigned short)(r >> 16);
}
__device__ __forceinline__ float bf2f(unsigned short b) {
    union { unsigned u; float f; } v; v.u = ((unsigned)b) << 16;
    return v.f;
}
__device__ __forceinline__ floatx4 mfma16(bf16x8 a, bf16x8 b, floatx4 c) {
    return __builtin_amdgcn_mfma_f32_16x16x32_bf16(a, b, c, 0, 0, 0);
}

// ===========================================================================
// Prep kernels (tiny; weights + bias only)
// ===========================================================================
__global__ void prep_bias(const int* __restrict__ rel_index,
                          const float* __restrict__ bias_table,
                          float* __restrict__ bias_pre) {
    int i = blockIdx.x * 256 + threadIdx.x;           // [6][144][144]
    if (i < NH * NT * NT) {
        int h = i / (NT * NT);
        int rem = i - h * (NT * NT);
        bias_pre[i] = bias_table[rel_index[rem] * NH + h];
    }
}

// wq frag: [h][j(6)][kt(6)][lane(64)][pos(8)]
__global__ void prep_wq_frag(const float* __restrict__ w_qkv,
                             unsigned short* __restrict__ wh,
                             unsigned short* __restrict__ wl) {
    int i = blockIdx.x * 256 + threadIdx.x;           // 6*6*6*512 = 110592
    if (i < NH * 6 * 6 * 512) {
        int h = i / 18432; int r = i - h * 18432;
        int j = r / 3072;  r -= j * 3072;
        int kt = r / 512;  r -= kt * 512;
        int lane = r >> 3, pos = r & 7;
        int col96 = j * 16 + (lane & 15);
        int k = kt * 32 + (lane >> 4) * 8 + pos;
        float v = w_qkv[k * WCOLS + (col96 >> 5) * DIM + h * HD + (col96 & 31)];
        unsigned short hi = f2bf(v);
        wh[i] = hi;
        wl[i] = f2bf(v - bf2f(hi));
    }
}

// wout frag: [nt(12)][kt(6)][lane(64)][pos(8)]
__global__ void prep_wo_frag(const float* __restrict__ w_out,
                             unsigned short* __restrict__ wh,
                             unsigned short* __restrict__ wl) {
    int i = blockIdx.x * 256 + threadIdx.x;           // 12*6*512 = 36864
    if (i < 12 * 6 * 512) {
        int nt = i / 3072; int r = i - nt * 3072;
        int kt = r / 512;  r -= kt * 512;
        int lane = r >> 3, pos = r & 7;
        int ocol = nt * 16 + (lane & 15);
        int k = kt * 32 + (lane >> 4) * 8 + pos;
        float v = w_out[k * DIM + ocol];
        unsigned short hi = f2bf(v);
        wh[i] = hi;
        wl[i] = f2bf(v - bf2f(hi));
    }
}

// ===========================================================================
// Fused: QKV + attention (6 heads) + out-proj, one block per window.
// 384 threads (6 waves). LDS (shorts, total 73120 = 146240 B):
//   XF [kt6][tile9][512] @0      (27648)  -- x bf16 A-frags; reused as O-frags
//   Q2 [hl2][tile9][512] @27648  (9216)
//   K2 [hl2][tile9][512] @36864  (9216)
//   V2t[4][slab5][512]   @46080  (10240)  -- (hl*2+ntv) groups
//   P  [wv6][slab5][512] @56320  (15360)
//   MB [144][5] u32      @71680  (1440 sh)
// ===========================================================================
__global__ __launch_bounds__(384, 2)
void fused(const float* __restrict__ x, const int* __restrict__ mask,
           const float* __restrict__ bias_pre,
           const unsigned short* __restrict__ wqh, const unsigned short* __restrict__ wql,
           const float* __restrict__ b_qkv,
           const unsigned short* __restrict__ woh_g, const unsigned short* __restrict__ wol_g,
           const float* __restrict__ b_out, float* __restrict__ out)
{
    __shared__ __align__(16) unsigned short lds[73120];
    const int XFo = 0, Q2o = 27648, K2o = 36864, V2o = 46080, Po = 56320, MBo = 71680;

    const int t = threadIdx.x;
    const int w = blockIdx.x;
    const int lane = t & 63, wv = t >> 6;
    const int c = lane & 15, q = lane >> 4;
    const float scale = 0.17677669529663687f;
    const float* xg = x + (size_t)w * NT * DIM;

    // ---- stage x -> XF bf16 A-frags (13824 dwords) ----
    {
        unsigned* XFd = (unsigned*)&lds[XFo];
        #pragma unroll
        for (int l = 0; l < 36; ++l) {
            int d = t + l * 384;
            int kt = d / 2304; int r2 = d - kt * 2304;
            int tile = r2 >> 8; int r3 = r2 & 255;
            int ln = r3 >> 2, pp = r3 & 3;
            int n = tile * 16 + (ln & 15);
            int k = kt * 32 + (ln >> 4) * 8 + pp * 2;
            float2 xv = *(const float2*)&xg[n * DIM + k];
            XFd[d] = (unsigned)f2bf(xv.x) | ((unsigned)f2bf(xv.y) << 16);
        }
    }
    // ---- zero pads: V2t tokens 144..159, P k 144..159 ----
    for (int e = t; e < 2560; e += 384) {
        if (e < 1024) {
            int gi = e >> 8, l2 = 32 + ((e >> 3) & 31), pos = e & 7;
            lds[V2o + (gi * 5 + 4) * 512 + l2 * 8 + pos] = 0;
        } else {
            int e2 = e - 1024;
            int wvi = e2 >> 8, l2 = 32 + ((e2 >> 3) & 31), pos = e2 & 7;
            lds[Po + (wvi * 5 + 4) * 512 + l2 * 8 + pos] = 0;
        }
    }
    // ---- mask -> bit-packed MB via ballot (coalesced, read once per window) ----
    {
        unsigned* mb = (unsigned*)&lds[MBo];
        for (int rr = 0; rr < 24; ++rr) {
            int n = wv * 24 + rr;
            const int* mrow = mask + ((size_t)w * NT + n) * NT;
            unsigned long long b0 = __ballot(mrow[lane] != 0);
            unsigned long long b1 = __ballot(mrow[64 + lane] != 0);
            int mv = (lane < 16) ? mrow[128 + lane] : 0;
            unsigned long long b2 = __ballot(mv != 0);
            if (lane == 0) {
                mb[n * 5 + 0] = (unsigned)b0;
                mb[n * 5 + 1] = (unsigned)(b0 >> 32);
                mb[n * 5 + 2] = (unsigned)b1;
                mb[n * 5 + 3] = (unsigned)(b1 >> 32);
                mb[n * 5 + 4] = (unsigned)b2;
            }
        }
    }

    const int part = wv % 3;        // phase-A role: 0=Q,1=K,2=V columns
    const int hlA  = wv / 3;        // phase-A head-in-group
    const int j0   = part * 2;
    const int hlB  = wv & 1;        // phase-B head-in-group
    const int s0   = wv >> 1;       // phase-B base strip

    floatx4 Oacc[3][3][2];

    #pragma unroll
    for (int g = 0; g < 3; ++g) {
        __syncthreads();            // XF/MB ready (g=0) / prev group's B reads done
        const int hg = 2 * g + hlA;

        // hoisted hi B-frags for this wave's 2 column-tiles
        const unsigned short* bh0p = wqh + (size_t)((hg * 6 + j0) * 6) * 512 + lane * 8;
        const unsigned short* bh1p = wqh + (size_t)((hg * 6 + j0 + 1) * 6) * 512 + lane * 8;
        const unsigned short* bl0p = wql + (size_t)((hg * 6 + j0) * 6) * 512 + lane * 8;
        const unsigned short* bl1p = wql + (size_t)((hg * 6 + j0 + 1) * 6) * 512 + lane * 8;
        bf16x8 bh0[6], bh1[6];
        #pragma unroll
        for (int kt = 0; kt < 6; ++kt) {
            bh0[kt] = *(const bf16x8*)&bh0p[kt * 512];
            bh1[kt] = *(const bf16x8*)&bh1p[kt * 512];
        }
        float bq0 = b_qkv[part * DIM + hg * HD + c];
        float bq1 = b_qkv[part * DIM + hg * HD + 16 + c];

        // ---- QKV gemm for this group's 2 column-tiles of this wave ----
        #pragma unroll
        for (int i3 = 0; i3 < 3; ++i3) {
            floatx4 a[3][2];
            #pragma unroll
            for (int ii = 0; ii < 3; ++ii) { a[ii][0] = (floatx4)0.0f; a[ii][1] = (floatx4)0.0f; }
            #pragma unroll
            for (int kt = 0; kt < 6; ++kt) {
                bf16x8 bl0 = *(const bf16x8*)&bl0p[kt * 512];
                bf16x8 bl1 = *(const bf16x8*)&bl1p[kt * 512];
                #pragma unroll
                for (int ii = 0; ii < 3; ++ii) {
                    bf16x8 ah = *(const bf16x8*)&lds[XFo + (kt * 9 + i3 * 3 + ii) * 512 + lane * 8];
                    a[ii][0] = mfma16(ah, bh0[kt], a[ii][0]);
                    a[ii][0] = mfma16(ah, bl0, a[ii][0]);
                    a[ii][1] = mfma16(ah, bh1[kt], a[ii][1]);
                    a[ii][1] = mfma16(ah, bl1, a[ii][1]);
                }
            }
            // scatter C-layout -> frag layouts (verified formulas from R3)
            #pragma unroll
            for (int ii = 0; ii < 3; ++ii) {
                int i = i3 * 3 + ii;
                #pragma unroll
                for (int r = 0; r < 4; ++r) {
                    float v0 = a[ii][0][r] + bq0;
                    float v1 = a[ii][1][r] + bq1;
                    if (part == 0) {
                        lds[Q2o + (hlA * 9 + i) * 512 + ((q * 4 + r) + 16 * (c >> 3)) * 8 + (c & 7)] = f2bf(v0 * scale);
                        lds[Q2o + (hlA * 9 + i) * 512 + ((q * 4 + r) + 16 * (2 + (c >> 3))) * 8 + (c & 7)] = f2bf(v1 * scale);
                    } else if (part == 1) {
                        lds[K2o + (hlA * 9 + i) * 512 + ((q * 4 + r) + 16 * (c >> 3)) * 8 + (c & 7)] = f2bf(v0);
                        lds[K2o + (hlA * 9 + i) * 512 + ((q * 4 + r) + 16 * (2 + (c >> 3))) * 8 + (c & 7)] = f2bf(v1);
                    } else {
                        int n = i * 16 + q * 4 + r;
                        lds[V2o + ((hlA * 2 + 0) * 5 + (n >> 5)) * 512 + (c + 16 * ((n >> 3) & 3)) * 8 + (n & 7)] = f2bf(v0);
                        lds[V2o + ((hlA * 2 + 1) * 5 + (n >> 5)) * 512 + (c + 16 * ((n >> 3) & 3)) * 8 + (n & 7)] = f2bf(v1);
                    }
                }
            }
        }
        __syncthreads();

        // ---- attention: 3 units/wave (even split), barrier-free ----
        const int hB = 2 * g + hlB;
        #pragma unroll
        for (int it = 0; it < 3; ++it) {
            int s = s0 + 3 * it;
            bf16x8 qf = *(const bf16x8*)&lds[Q2o + (hlB * 9 + s) * 512 + lane * 8];
            floatx4 sacc[9];
            #pragma unroll
            for (int nt = 0; nt < 9; ++nt) {
                bf16x8 kf = *(const bf16x8*)&lds[K2o + (hlB * 9 + nt) * 512 + lane * 8];
                sacc[nt] = mfma16(qf, kf, (floatx4)0.0f);
            }
            const unsigned* mb = (const unsigned*)&lds[MBo];
            #pragma unroll
            for (int r = 0; r < 4; ++r) {
                int n = s * 16 + q * 4 + r;
                const float* brow = bias_pre + hB * (NT * NT) + n * NT;
                unsigned mwv[5];
                #pragma unroll
                for (int k5 = 0; k5 < 5; ++k5) mwv[k5] = mb[n * 5 + k5];
                float e[9]; float mx = -1e30f;
                #pragma unroll
                for (int nt = 0; nt < 9; ++nt) {
                    float val = sacc[nt][r] + brow[nt * 16 + c];
                    unsigned bit = (mwv[nt >> 1] >> (((nt & 1) << 4) + c)) & 1u;
                    val = bit ? val : -1e9f;
                    e[nt] = val; mx = fmaxf(mx, val);
                }
                #pragma unroll
                for (int o = 8; o; o >>= 1) mx = fmaxf(mx, __shfl_xor(mx, o, 64));
                float sum = 0.f;
                #pragma unroll
                for (int nt = 0; nt < 9; ++nt) { e[nt] = __expf(e[nt] - mx); sum += e[nt]; }
                #pragma unroll
                for (int o = 8; o; o >>= 1) sum += __shfl_xor(sum, o, 64);
                float rinv = 1.0f / sum;
                #pragma unroll
                for (int nt = 0; nt < 9; ++nt) {
                    int col = nt * 16 + c;
                    lds[Po + (wv * 5 + (col >> 5)) * 512 +
                        ((q * 4 + r) + 16 * ((col >> 3) & 3)) * 8 + (col & 7)] = f2bf(e[nt] * rinv);
                }
            }
            floatx4 o0 = (floatx4)0.0f, o1 = (floatx4)0.0f;
            #pragma unroll
            for (int sl = 0; sl < 5; ++sl) {
                bf16x8 pf = *(const bf16x8*)&lds[Po + (wv * 5 + sl) * 512 + lane * 8];
                o0 = mfma16(pf, *(const bf16x8*)&lds[V2o + ((hlB * 2 + 0) * 5 + sl) * 512 + lane * 8], o0);
                o1 = mfma16(pf, *(const bf16x8*)&lds[V2o + ((hlB * 2 + 1) * 5 + sl) * 512 + lane * 8], o1);
            }
            Oacc[g][it][0] = o0; Oacc[g][it][1] = o1;
        }
    }

    // ---- phase C: O C-layout -> A-frags in XF region (x no longer needed) ----
    #pragma unroll
    for (int g = 0; g < 3; ++g) {
        int hB = 2 * g + hlB;
        #pragma unroll
        for (int it = 0; it < 3; ++it) {
            int s = s0 + 3 * it;
            #pragma unroll
            for (int ntv = 0; ntv < 2; ++ntv) {
                #pragma unroll
                for (int r = 0; r < 4; ++r) {
                    lds[XFo + (hB * 9 + s) * 512 +
                        ((q * 4 + r) + 16 * (ntv * 2 + (c >> 3))) * 8 + (c & 7)] =
                        f2bf(Oacc[g][it][ntv][r]);
                }
            }
        }
    }
    __syncthreads();

    // ---- out-proj: wave owns 2 output col-tiles ----
    {
        const int colt0 = 2 * wv;
        const unsigned short* wh0p = woh_g + (size_t)(colt0 * 6) * 512 + lane * 8;
        const unsigned short* wh1p = woh_g + (size_t)((colt0 + 1) * 6) * 512 + lane * 8;
        const unsigned short* wl0p = wol_g + (size_t)(colt0 * 6) * 512 + lane * 8;
        const unsigned short* wl1p = wol_g + (size_t)((colt0 + 1) * 6) * 512 + lane * 8;
        bf16x8 wh0[6], wh1[6];
        #pragma unroll
        for (int kt = 0; kt < 6; ++kt) {
            wh0[kt] = *(const bf16x8*)&wh0p[kt * 512];
            wh1[kt] = *(const bf16x8*)&wh1p[kt * 512];
        }
        float bo0 = b_out[colt0 * 16 + c];
        float bo1 = b_out[colt0 * 16 + 16 + c];
        #pragma unroll
        for (int i3 = 0; i3 < 3; ++i3) {
            floatx4 a2[3][2];
            #pragma unroll
            for (int ii = 0; ii < 3; ++ii) { a2[ii][0] = (floatx4)0.0f; a2[ii][1] = (floatx4)0.0f; }
            #pragma unroll
            for (int kt = 0; kt < 6; ++kt) {
                bf16x8 wlo0 = *(const bf16x8*)&wl0p[kt * 512];
                bf16x8 wlo1 = *(const bf16x8*)&wl1p[kt * 512];
                #pragma unroll
                for (int ii = 0; ii < 3; ++ii) {
                    bf16x8 af = *(const bf16x8*)&lds[XFo + (kt * 9 + i3 * 3 + ii) * 512 + lane * 8];
                    a2[ii][0] = mfma16(af, wh0[kt], a2[ii][0]);
                    a2[ii][0] = mfma16(af, wlo0, a2[ii][0]);
                    a2[ii][1] = mfma16(af, wh1[kt], a2[ii][1]);
                    a2[ii][1] = mfma16(af, wlo1, a2[ii][1]);
                }
            }
            #pragma unroll
            for (int ii = 0; ii < 3; ++ii) {
                int n0 = (i3 * 3 + ii) * 16 + q * 4;
                #pragma unroll
                for (int r = 0; r < 4; ++r) {
                    size_t ro = ((size_t)w * NT + n0 + r) * DIM;
                    out[ro + colt0 * 16 + c] = a2[ii][0][r] + bo0;
                    out[ro + colt0 * 16 + 16 + c] = a2[ii][1][r] + bo1;
                }
            }
        }
    }
}

// ===========================================================================
// Zero-ws fallback (R1 fp32 kernels, verified)
// ===========================================================================
__global__ __launch_bounds__(256, 2)
void attn_kernel(const float* __restrict__ x, const int* __restrict__ mask,
                 const int* __restrict__ rel_index, const float* __restrict__ w_qkv,
                 const float* __restrict__ b_qkv, const float* __restrict__ bias_table,
                 float* __restrict__ out)
{
    __shared__ float smem[19136];
    float* xt = smem;
    float* wt = smem + 4768;
    float* qs = smem;
    float* ks = smem + 4752;
    float* vs = smem + 9504;
    float* S  = smem + 14400;

    const int t  = threadIdx.x;
    const int w  = blockIdx.x / NH;
    const int h  = blockIdx.x % NH;
    const int tx = t & 15;
    const int ty = t >> 4;
    const float scale = 0.17677669529663687f;
    const float* xg = x + (size_t)w * NT * DIM;

    float acc[9][6];
    #pragma unroll
    for (int i = 0; i < 9; ++i)
        #pragma unroll
        for (int j = 0; j < 6; ++j) acc[i][j] = 0.f;

    for (int kt = 0; kt < 6; ++kt) {
        #pragma unroll
        for (int l = 0; l < 18; ++l) {
            int e = t + l * 256;
            int n = e >> 5, kk = e & 31;
            xt[kk * 149 + n] = xg[n * DIM + kt * 32 + kk];
        }
        #pragma unroll
        for (int l = 0; l < 12; ++l) {
            int e = t + l * 256;
            int kk = e / 96, cc = e - kk * 96;
            int col = (cc >> 5) * DIM + h * HD + (cc & 31);
            wt[kk * 96 + cc] = w_qkv[(kt * 32 + kk) * WCOLS + col];
        }
        __syncthreads();
        #pragma unroll
        for (int kk = 0; kk < 32; ++kk) {
            float a[9], b[6];
            #pragma unroll
            for (int i = 0; i < 9; ++i) a[i] = xt[kk * 149 + ty * 9 + i];
            #pragma unroll
            for (int j = 0; j < 6; ++j) b[j] = wt[kk * 96 + tx * 6 + j];
            #pragma unroll
            for (int i = 0; i < 9; ++i)
                #pragma unroll
                for (int j = 0; j < 6; ++j) acc[i][j] = fmaf(a[i], b[j], acc[i][j]);
        }
        __syncthreads();
    }

    #pragma unroll
    for (int j = 0; j < 6; ++j) {
        int cc = tx * 6 + j;
        int part = cc >> 5, jj = cc & 31;
        float bq = b_qkv[part * DIM + h * HD + jj];
        #pragma unroll
        for (int i = 0; i < 9; ++i) {
            int r = ty * 9 + i;
            float val = acc[i][j] + bq;
            if (part == 0)      qs[r * 33 + jj] = val * scale;
            else if (part == 1) ks[r * 33 + jj] = val;
            else                vs[r * 34 + jj] = val;
        }
    }
    __syncthreads();

    const int wave = t >> 6, lane = t & 63;
    for (int rt = 0; rt < 5; ++rt) {
        const int rows = (rt == 4) ? 16 : 32;
        {
            int r0 = ty * 2;
            int n0 = rt * 32 + r0; if (n0 > NT - 1) n0 = NT - 1;
            int n1 = n0 + 1;       if (n1 > NT - 1) n1 = NT - 1;
            int m0 = tx * 9;
            float s0[9], s1[9];
            #pragma unroll
            for (int j = 0; j < 9; ++j) { s0[j] = 0.f; s1[j] = 0.f; }
            #pragma unroll
            for (int kk = 0; kk < 32; ++kk) {
                float a0 = qs[n0 * 33 + kk];
                float a1 = qs[n1 * 33 + kk];
                #pragma unroll
                for (int j = 0; j < 9; ++j) {
                    float bk = ks[(m0 + j) * 33 + kk];
                    s0[j] = fmaf(a0, bk, s0[j]);
                    s1[j] = fmaf(a1, bk, s1[j]);
                }
            }
            if (r0 < rows) {
                #pragma unroll
                for (int j = 0; j < 9; ++j) S[r0 * 148 + m0 + j] = s0[j];
                #pragma unroll
                for (int j = 0; j < 9; ++j) S[(r0 + 1) * 148 + m0 + j] = s1[j];
            }
        }
        __syncthreads();

        for (int r = wave; r < rows; r += 4) {
            int n = rt * 32 + r;
            const int* mrow = mask + ((size_t)w * NT + n) * NT;
            const int* rrow = rel_index + n * NT;
            float e0 = S[r * 148 + lane] + bias_table[rrow[lane] * NH + h];
            if (mrow[lane] == 0) e0 = -1e9f;
            float e1 = S[r * 148 + 64 + lane] + bias_table[rrow[64 + lane] * NH + h];
            if (mrow[64 + lane] == 0) e1 = -1e9f;
            float e2 = -INFINITY;
            if (lane < 16) {
                e2 = S[r * 148 + 128 + lane] + bias_table[rrow[128 + lane] * NH + h];
                if (mrow[128 + lane] == 0) e2 = -1e9f;
            }
            float vmax = fmaxf(fmaxf(e0, e1), e2);
            #pragma unroll
            for (int off = 32; off > 0; off >>= 1)
                vmax = fmaxf(vmax, __shfl_xor(vmax, off, 64));
            float p0 = __expf(e0 - vmax);
            float p1 = __expf(e1 - vmax);
            float p2 = (lane < 16) ? __expf(e2 - vmax) : 0.f;
            float s = p0 + p1 + p2;
            #pragma unroll
            for (int off = 32; off > 0; off >>= 1)
                s += __shfl_xor(s, off, 64);
            float rinv = 1.f / s;
            S[r * 148 + lane] = p0 * rinv;
            S[r * 148 + 64 + lane] = p1 * rinv;
            if (lane < 16) S[r * 148 + 128 + lane] = p2 * rinv;
        }
        __syncthreads();

        {
            int r0 = ty * 2, dd0 = tx * 2;
            if (r0 < rows) {
                float o00 = 0, o01 = 0, o10 = 0, o11 = 0;
                #pragma unroll
                for (int m = 0; m < NT; ++m) {
                    float p0 = S[r0 * 148 + m];
                    float p1 = S[(r0 + 1) * 148 + m];
                    float2 vv = *(const float2*)&vs[m * 34 + dd0];
                    o00 = fmaf(p0, vv.x, o00);
                    o01 = fmaf(p0, vv.y, o01);
                    o10 = fmaf(p1, vv.x, o10);
                    o11 = fmaf(p1, vv.y, o11);
                }
                int n0 = rt * 32 + r0;
                *(float2*)&out[((size_t)(w * NT + n0)) * DIM + h * HD + dd0] = make_float2(o00, o01);
                *(float2*)&out[((size_t)(w * NT + n0 + 1)) * DIM + h * HD + dd0] = make_float2(o10, o11);
            }
        }
        __syncthreads();
    }
}

__global__ __launch_bounds__(256, 2)
void proj_kernel(float* __restrict__ io, const float* __restrict__ w_out,
                 const float* __restrict__ b_out)
{
    __shared__ float in_t[64 * 196];
    __shared__ float wt[32 * 192];
    const int t = threadIdx.x;
    const size_t row0 = (size_t)blockIdx.x * 64;

    #pragma unroll
    for (int l = 0; l < 12; ++l) {
        int e = t + l * 256;
        int r = e / 48, c4 = e - r * 48;
        float4 val = *(const float4*)&io[(row0 + r) * DIM + c4 * 4];
        *(float4*)&in_t[r * 196 + c4 * 4] = val;
    }
    const int tx = t & 15, ty = t >> 4;
    float acc[4][12];
    #pragma unroll
    for (int i = 0; i < 4; ++i)
        #pragma unroll
        for (int j = 0; j < 12; ++j) acc[i][j] = 0.f;

    for (int kt = 0; kt < 6; ++kt) {
        __syncthreads();
        #pragma unroll
        for (int l = 0; l < 6; ++l) {
            int e = t + l * 256;
            int kk = e / 48, c4 = e - kk * 48;
            *(float4*)&wt[kk * 192 + c4 * 4] =
                *(const float4*)&w_out[(kt * 32 + kk) * DIM + c4 * 4];
        }
        __syncthreads();
        #pragma unroll
        for (int kk = 0; kk < 32; ++kk) {
            float a[4];
            #pragma unroll
            for (int i = 0; i < 4; ++i) a[i] = in_t[(ty * 4 + i) * 196 + kt * 32 + kk];
            float b[12];
            #pragma unroll
            for (int j4 = 0; j4 < 3; ++j4) {
                float4 bb = *(const float4*)&wt[kk * 192 + tx * 12 + j4 * 4];
                b[j4 * 4] = bb.x; b[j4 * 4 + 1] = bb.y;
                b[j4 * 4 + 2] = bb.z; b[j4 * 4 + 3] = bb.w;
            }
            #pragma unroll
            for (int i = 0; i < 4; ++i)
                #pragma unroll
                for (int j = 0; j < 12; ++j)
                    acc[i][j] = fmaf(a[i], b[j], acc[i][j]);
        }
    }

    float bo[12];
    #pragma unroll
    for (int j4 = 0; j4 < 3; ++j4) {
        float4 bb = *(const float4*)&b_out[tx * 12 + j4 * 4];
        bo[j4 * 4] = bb.x; bo[j4 * 4 + 1] = bb.y;
        bo[j4 * 4 + 2] = bb.z; bo[j4 * 4 + 3] = bb.w;
    }
    #pragma unroll
    for (int i = 0; i < 4; ++i) {
        size_t r = row0 + ty * 4 + i;
        #pragma unroll
        for (int j4 = 0; j4 < 3; ++j4) {
            float4 o;
            o.x = acc[i][j4 * 4]     + bo[j4 * 4];
            o.y = acc[i][j4 * 4 + 1] + bo[j4 * 4 + 1];
            o.z = acc[i][j4 * 4 + 2] + bo[j4 * 4 + 2];
            o.w = acc[i][j4 * 4 + 3] + bo[j4 * 4 + 3];
            *(float4*)&io[r * DIM + tx * 12 + j4 * 4] = o;
        }
    }
}

// ===========================================================================
extern "C" void kernel_launch(void* const* d_in, const int* in_sizes, int n_in,
                              void* d_out, int out_size, void* d_ws, size_t ws_size,
                              hipStream_t stream) {
    const float* x          = (const float*)d_in[0];
    const int*   mask       = (const int*)d_in[1];
    const int*   rel_index  = (const int*)d_in[2];
    const float* w_qkv      = (const float*)d_in[3];
    const float* b_qkv      = (const float*)d_in[4];
    const float* w_out      = (const float*)d_in[5];
    const float* b_out      = (const float*)d_in[6];
    const float* bias_table = (const float*)d_in[7];
    float* out = (float*)d_out;

    // ws layout (bytes):
    //   bias_pre @0        : 497664
    //   wq_h     @497664   : 221184   (frag layout)
    //   wq_l     @718848   : 221184
    //   wo_h     @940032   :  73728   (frag layout)
    //   wo_l     @1013760  :  73728   -> total 1087488
    const size_t WS_NEED = 1087488;

    if (ws_size >= WS_NEED) {
        char* ws = (char*)d_ws;
        float*          bias_pre = (float*)ws;
        unsigned short* wq_h     = (unsigned short*)(ws + 497664);
        unsigned short* wq_l     = (unsigned short*)(ws + 718848);
        unsigned short* wo_h     = (unsigned short*)(ws + 940032);
        unsigned short* wo_l     = (unsigned short*)(ws + 1013760);

        hipLaunchKernelGGL(prep_bias, dim3(486), dim3(256), 0, stream,
                           rel_index, bias_table, bias_pre);
        hipLaunchKernelGGL(prep_wq_frag, dim3(432), dim3(256), 0, stream,
                           w_qkv, wq_h, wq_l);
        hipLaunchKernelGGL(prep_wo_frag, dim3(144), dim3(256), 0, stream,
                           w_out, wo_h, wo_l);
        hipLaunchKernelGGL(fused, dim3(NW), dim3(384), 0, stream,
                           x, mask, bias_pre, wq_h, wq_l, b_qkv,
                           wo_h, wo_l, b_out, out);
    } else {
        hipLaunchKernelGGL(attn_kernel, dim3(NW * NH), dim3(256), 0, stream,
                           x, mask, rel_index, w_qkv, b_qkv, bias_table, out);
        hipLaunchKernelGGL(proj_kernel, dim3(NW * NT / 64), dim3(256), 0, stream,
                           out, w_out, b_out);
    }
}